// Round 5
// baseline (349.358 us; speedup 1.0000x reference)
//
#include <hip/hip_runtime.h>
#include <math.h>

#define N_NODES 100000
#define N_EDGES 800000
#define D_IN    64
#define HC      128   // H*C
#define CAP     48    // max in-degree slots (Poisson(8): P(>48) ~ 0)

#define GEMM_BLOCKS 1563                 // ceil(100000/64)
#define FUSED_BLOCKS (3 * GEMM_BLOCKS)   // bid%3==2 -> gemm, else scatter

// tanh-approx gelu (jax.nn.gelu default approximate=True)
__device__ __forceinline__ float gelu_f(float x) {
    float x3 = x * x * x;
    float y  = 0.7978845608028654f * (x + 0.044715f * x3);
    float t = 1.0f - 2.0f / (__expf(2.0f * y) + 1.0f);
    return 0.5f * x * (1.0f + t);
}

// sum across a 16-lane row via DPP row_ror (pure VALU, no ds_swizzle)
__device__ __forceinline__ float red16(float x) {
    x += __int_as_float(__builtin_amdgcn_mov_dpp(__float_as_int(x), 0x128, 0xF, 0xF, true)); // ror:8
    x += __int_as_float(__builtin_amdgcn_mov_dpp(__float_as_int(x), 0x124, 0xF, 0xF, true)); // ror:4
    x += __int_as_float(__builtin_amdgcn_mov_dpp(__float_as_int(x), 0x122, 0xF, 0xF, true)); // ror:2
    x += __int_as_float(__builtin_amdgcn_mov_dpp(__float_as_int(x), 0x121, 0xF, 0xF, true)); // ror:1
    return x;
}

__device__ __forceinline__ float4 ldW(const float* __restrict__ Wl,
                                      const float* __restrict__ Wr,
                                      int stage, int f) {
    int kk = f >> 6, c4 = f & 63;
    const float* src = (c4 < 32)
        ? (Wl + (size_t)(32 * stage + kk) * HC + 4 * c4)
        : (Wr + (size_t)(32 * stage + kk) * HC + 4 * (c4 - 32));
    return *(const float4*)src;
}

// ---------------- fused GEMM (+ scatter role) -------------------------------
// GEMM [N,64]@[64,256]: block = 64 nodes; thread = 8 nodes x {XL 4ch, XR 4ch}.
// Round-4 failure: VGPR=84 -> compiler couldn't hoist next-k ds_reads above
// the FMA block -> read/wait/fma serialization, VALUBusy 31%. Fix: EXPLICIT
// software pipeline (named next-k registers, read->use distance = 64 FMAs
// ~128cy >= LDS latency) + stage-1 W global loads issued before inner loop 0
// (latency hidden under 8192cy of FMA). ~140 VGPR by construction.
__global__ __launch_bounds__(256, 3) void gemm_scatter_kernel(
    const float* __restrict__ X,
    const float* __restrict__ Wl, const float* __restrict__ bl,
    const float* __restrict__ Wr, const float* __restrict__ br,
    float* __restrict__ XL, float* __restrict__ XR,
    const int* __restrict__ edges, int* __restrict__ cnt, int* __restrict__ tbl,
    int fused) {
    __shared__ float XT[64 * 68];     // [k][n], stride 68 keeps 16B rows
    __shared__ float WS[32 * 256];    // [kk][c]; c<128: Wl, c>=128: Wr

    const int t = threadIdx.x;
    int gid;
    if (fused) {
        const int g = blockIdx.x / 3, r = blockIdx.x % 3;
        if (r != 2) {                      // ---- scatter role ----
            const int e = (2 * g + r) * 256 + t;
            if (e < N_EDGES) {
                int s = edges[e];
                int d = edges[N_EDGES + e];
                int slot = atomicAdd(&cnt[d], 1);
                if (slot < CAP) tbl[d * CAP + slot] = s;
            }
            return;
        }
        gid = g;
    } else {
        gid = blockIdx.x;
    }
    const int n0 = gid * 64;

    // issue X tile loads (coalesced)
    float4 xv[4];
    int xn[4], xk[4];
    #pragma unroll
    for (int p = 0; p < 4; ++p) {
        int f = p * 256 + t;
        xn[p] = f >> 4; xk[p] = f & 15;
        int gn = n0 + xn[p];
        xv[p] = make_float4(0.0f, 0.0f, 0.0f, 0.0f);
        if (gn < N_NODES) xv[p] = *(const float4*)(X + (size_t)gn * D_IN + 4 * xk[p]);
    }
    // issue W stage-0 loads
    float4 w0[8];
    #pragma unroll
    for (int p = 0; p < 8; ++p) w0[p] = ldW(Wl, Wr, 0, p * 256 + t);

    // write XT (transpose; one-time ~8-way conflict, ~2us total, accepted)
    #pragma unroll
    for (int p = 0; p < 4; ++p) {
        XT[(4 * xk[p] + 0) * 68 + xn[p]] = xv[p].x;
        XT[(4 * xk[p] + 1) * 68 + xn[p]] = xv[p].y;
        XT[(4 * xk[p] + 2) * 68 + xn[p]] = xv[p].z;
        XT[(4 * xk[p] + 3) * 68 + xn[p]] = xv[p].w;
    }
    // write WS stage 0; col 4*c4 holds both halves (c4>=32 lands at 128+)
    #pragma unroll
    for (int p = 0; p < 8; ++p) {
        int f = p * 256 + t;
        *(float4*)&WS[(f >> 6) * 256 + 4 * (f & 63)] = w0[p];
    }
    // issue W stage-1 loads NOW; consumed after inner loop 0 (~8200cy later)
    #pragma unroll
    for (int p = 0; p < 8; ++p) w0[p] = ldW(Wl, Wr, 1, p * 256 + t);

    const int cg = t & 31;            // ch 4cg..4cg+3 of both XL and XR
    const int mg = t >> 5;            // nodes mg*8..+7

    const float4 bL = *(const float4*)(bl + 4 * cg);
    const float4 bR = *(const float4*)(br + 4 * cg);
    float4 accL[8], accR[8];
    #pragma unroll
    for (int m = 0; m < 8; ++m) { accL[m] = bL; accR[m] = bR; }

    const float* wq = &WS[4 * cg];

    // explicit software-pipelined inner loop (see header comment)
#define GEMM_INNER(SBASE)                                                    \
    {                                                                        \
        const float* xq = &XT[(SBASE) * 68 + 8 * mg];                        \
        float4 xa = *(const float4*)(xq);                                    \
        float4 xb = *(const float4*)(xq + 4);                                \
        float4 cl = *(const float4*)(wq);                                    \
        float4 cr = *(const float4*)(wq + 128);                              \
        _Pragma("unroll 1")                                                  \
        for (int kk = 0; kk < 32; ++kk) {                                    \
            int kn = kk < 31 ? kk + 1 : 31;                                  \
            float4 nxa = *(const float4*)(xq + kn * 68);                     \
            float4 nxb = *(const float4*)(xq + kn * 68 + 4);                 \
            float4 ncl = *(const float4*)(wq + kn * 256);                    \
            float4 ncr = *(const float4*)(wq + kn * 256 + 128);              \
            float xm[8] = {xa.x, xa.y, xa.z, xa.w, xb.x, xb.y, xb.z, xb.w};  \
            _Pragma("unroll")                                                \
            for (int m = 0; m < 8; ++m) {                                    \
                accL[m].x = fmaf(xm[m], cl.x, accL[m].x);                    \
                accL[m].y = fmaf(xm[m], cl.y, accL[m].y);                    \
                accL[m].z = fmaf(xm[m], cl.z, accL[m].z);                    \
                accL[m].w = fmaf(xm[m], cl.w, accL[m].w);                    \
                accR[m].x = fmaf(xm[m], cr.x, accR[m].x);                    \
                accR[m].y = fmaf(xm[m], cr.y, accR[m].y);                    \
                accR[m].z = fmaf(xm[m], cr.z, accR[m].z);                    \
                accR[m].w = fmaf(xm[m], cr.w, accR[m].w);                    \
            }                                                                \
            xa = nxa; xb = nxb; cl = ncl; cr = ncr;                          \
        }                                                                    \
    }

    __syncthreads();
    GEMM_INNER(0)
    __syncthreads();
    // write WS stage 1 (loads issued ~8200cy ago -> vmcnt already drained)
    #pragma unroll
    for (int p = 0; p < 8; ++p) {
        int f = p * 256 + t;
        *(float4*)&WS[(f >> 6) * 256 + 4 * (f & 63)] = w0[p];
    }
    __syncthreads();
    GEMM_INNER(32)

    #pragma unroll
    for (int m = 0; m < 8; ++m) {
        int n = n0 + mg * 8 + m;
        if (n < N_NODES) {
            *(float4*)(XL + (size_t)n * HC + 4 * cg) = accL[m];
            *(float4*)(XR + (size_t)n * HC + 4 * cg) = accR[m];
        }
    }
#undef GEMM_INNER
}

// ---------------- aggregation: 2 NODES per wave, 1 edge/iter per half -------
// Half-wave (32 lanes) owns one node: lanes 0-15 head0, 16-31 head1, lane li
// holds channels 4li..4li+3. Round-4 showed VALUBusy 80% (issue-bound) with
// prologue+epilogue ~40% of wave slots -> amortize them over 2 nodes/wave.
// No cross-stream merge needed anymore. Fixed-shift softmax (m0 = self score,
// log2 domain, exp2f). Slots >=32 (P~1e-11/node) read tbl directly.
__global__ __launch_bounds__(256) void aggregate_kernel(
    const float* __restrict__ XL, const float* __restrict__ XR,
    const int* __restrict__ cnt, const int* __restrict__ tbl,
    const float* __restrict__ att, const float* __restrict__ bias,
    float* __restrict__ Y, int applyGelu) {
    const int wv   = (blockIdx.x * blockDim.x + threadIdx.x) >> 6;
    const int lane = threadIdx.x & 63;
    const int v    = 2 * wv + (lane >> 5);      // node per 32-lane half
    if (v >= N_NODES) return;
    const int li = lane & 15;
    const int hc = ((lane >> 4) & 1) * 64 + 4 * li;
    const int selbase = lane & 32;              // shfl source base for my half

    float4 a4 = *(const float4*)(att + hc);
    a4.x *= 1.44269504f; a4.y *= 1.44269504f;   // log2(e): scores in log2
    a4.z *= 1.44269504f; a4.w *= 1.44269504f;
    const float4 xr4 = *(const float4*)(XR + (size_t)v * HC + hc);
    const float4 xl4 = *(const float4*)(XL + (size_t)v * HC + hc);

    // self edge score = shift m0; contributes exp2(0)=1 and xl4
    float z0 = xl4.x + xr4.x, z1 = xl4.y + xr4.y;
    float z2 = xl4.z + xr4.z, z3 = xl4.w + xr4.w;
    float p = fmaxf(z0, 0.2f*z0) * a4.x + fmaxf(z1, 0.2f*z1) * a4.y
            + fmaxf(z2, 0.2f*z2) * a4.z + fmaxf(z3, 0.2f*z3) * a4.w;
    const float m0 = red16(p);

    float s = 1.0f;
    float ax = xl4.x, ay = xl4.y, az = xl4.z, aw = xl4.w;

    int deg = cnt[v];
    if (deg > CAP) deg = CAP;
    const int slot = lane & 31;
    int u_l = (slot < deg) ? tbl[v * CAP + slot] : 0;

    int dmax = deg;
    { int d2 = __shfl_xor(deg, 32); dmax = d2 > dmax ? d2 : dmax; }

    const float* __restrict__ XLh = XL + hc;

    // depth-3 prefetch (per half)
    float4 x0 = make_float4(0,0,0,0), x1 = x0, x2 = x0;
    if (dmax > 0) { int u = __shfl(u_l, 0 + selbase); x0 = *(const float4*)(XLh + (size_t)u * HC); }
    if (dmax > 1) { int u = __shfl(u_l, 1 + selbase); x1 = *(const float4*)(XLh + (size_t)u * HC); }
    if (dmax > 2) { int u = __shfl(u_l, 2 + selbase); x2 = *(const float4*)(XLh + (size_t)u * HC); }

    for (int i = 0; i < dmax; ++i) {
        float4 xc = x0; x0 = x1; x1 = x2;
        int pf = i + 3;
        if (pf < dmax) {
            int u = (pf < 32) ? __shfl(u_l, pf + selbase) : tbl[v * CAP + pf];
            x2 = *(const float4*)(XLh + (size_t)u * HC);
        }
        z0 = xc.x + xr4.x; z1 = xc.y + xr4.y;
        z2 = xc.z + xr4.z; z3 = xc.w + xr4.w;
        p = fmaxf(z0, 0.2f*z0) * a4.x + fmaxf(z1, 0.2f*z1) * a4.y
          + fmaxf(z2, 0.2f*z2) * a4.z + fmaxf(z3, 0.2f*z3) * a4.w;
        p = red16(p);
        if (i >= deg) p = -1e30f;               // other half longer -> mask
        float w = exp2f(p - m0);
        s += w;
        ax = fmaf(w, xc.x, ax); ay = fmaf(w, xc.y, ay);
        az = fmaf(w, xc.z, az); aw = fmaf(w, xc.w, aw);
    }

    float inv = 1.0f / (s + 1e-16f);
    ax *= inv; ay *= inv; az *= inv; aw *= inv;

    // mean over heads (head1 sits at lane^16 within the half)
    ax += __shfl_xor(ax, 16); ay += __shfl_xor(ay, 16);
    az += __shfl_xor(az, 16); aw += __shfl_xor(aw, 16);
    ax *= 0.5f; ay *= 0.5f; az *= 0.5f; aw *= 0.5f;

    if ((lane & 31) < 16) {
        const float4 b4 = *(const float4*)(bias + 4 * li);
        ax += b4.x; ay += b4.y; az += b4.z; aw += b4.w;
        if (applyGelu) { ax = gelu_f(ax); ay = gelu_f(ay); az = gelu_f(az); aw = gelu_f(aw); }
        *(float4*)(Y + (size_t)v * 64 + 4 * li) = make_float4(ax, ay, az, aw);
    }
}

extern "C" void kernel_launch(void* const* d_in, const int* in_sizes, int n_in,
                              void* d_out, int out_size, void* d_ws, size_t ws_size,
                              hipStream_t stream) {
    const float* X     = (const float*)d_in[0];
    const int*   edges = (const int*)d_in[1];
    const float* Wl    = (const float*)d_in[2];
    const float* bl    = (const float*)d_in[3];
    const float* Wr    = (const float*)d_in[4];
    const float* br    = (const float*)d_in[5];
    const float* att   = (const float*)d_in[6];
    const float* bias  = (const float*)d_in[7];

    char* ws = (char*)d_ws;
    float* XLb = (float*)ws;                                          // N*128 f32
    float* XRb = (float*)(ws + (size_t)N_NODES * HC * 4);             // N*128 f32
    float* Yb  = (float*)(ws + (size_t)N_NODES * HC * 8);             // N*64 f32
    int*   cnt = (int*)(ws + (size_t)N_NODES * HC * 8 + (size_t)N_NODES * 64 * 4);
    int*   tbl = cnt + N_NODES;                                       // N*CAP ints

    hipMemsetAsync(cnt, 0, N_NODES * sizeof(int), stream);

    const int agg_grid = ((N_NODES + 1) / 2 * 64 + 255) / 256;        // 2 nodes/wave

    // layer 0: gemm + scatter fused (disjoint pipes: VALU/LDS vs atomics)
    gemm_scatter_kernel<<<FUSED_BLOCKS, 256, 0, stream>>>(
        X, Wl, bl, Wr, br, XLb, XRb, edges, cnt, tbl, 1);
    aggregate_kernel<<<agg_grid, 256, 0, stream>>>(XLb, XRb, cnt, tbl, att, bias, Yb, 1);
    // layer 1
    gemm_scatter_kernel<<<GEMM_BLOCKS, 256, 0, stream>>>(
        Yb, Wl + 8192, bl + 128, Wr + 8192, br + 128, XLb, XRb, edges, cnt, tbl, 0);
    aggregate_kernel<<<agg_grid, 256, 0, stream>>>(XLb, XRb, cnt, tbl, att + 128, bias + 64,
                                                   (float*)d_out, 0);
}